// Round 1
// baseline (5350.623 us; speedup 1.0000x reference)
//
#include <hip/hip_runtime.h>
#include <math.h>

#define B_    256
#define S_    50
#define I_    1024
#define H_    512
#define G3_   1536   // 3*H
#define SENT_ 512
#define DOC_  1024

__device__ __forceinline__ float sigf(float x) { return 1.0f / (1.0f + __expf(-x)); }

// ---------------------------------------------------------------------------
// Generic tiled fp32 GEMM:  C[m,n] = act(dot(A[m,:], W[n,:]) + bias[n])
// A: [M,K] row-major, W: [N,K] row-major (i.e. C = A @ W.T), C: [M,N].
// Tiles: 64x64, BK=16, 256 threads, 4x4 microtile. M,N,K multiples of 64/16.
// ACT: 0 = none, 1 = relu, 2 = tanh
// ---------------------------------------------------------------------------
template <int ACT>
__global__ __launch_bounds__(256) void gemm_nt(const float* __restrict__ A,
                                               const float* __restrict__ W,
                                               const float* __restrict__ bias,
                                               float* __restrict__ C, int N, int K) {
  __shared__ float As[16][68];
  __shared__ float Bs[16][68];
  const int t = threadIdx.x;
  const int tx = t & 15, ty = t >> 4;
  const int m0 = blockIdx.y * 64, n0 = blockIdx.x * 64;
  const int lr = t >> 2, lc = t & 3;
  const float* Arow = A + (size_t)(m0 + lr) * K;
  const float* Wrow = W + (size_t)(n0 + lr) * K;
  float acc[4][4] = {};
  for (int kc = 0; kc < K; kc += 16) {
    float4 av = *(const float4*)(Arow + kc + lc * 4);
    float4 wv = *(const float4*)(Wrow + kc + lc * 4);
    As[lc * 4 + 0][lr] = av.x; As[lc * 4 + 1][lr] = av.y;
    As[lc * 4 + 2][lr] = av.z; As[lc * 4 + 3][lr] = av.w;
    Bs[lc * 4 + 0][lr] = wv.x; Bs[lc * 4 + 1][lr] = wv.y;
    Bs[lc * 4 + 2][lr] = wv.z; Bs[lc * 4 + 3][lr] = wv.w;
    __syncthreads();
#pragma unroll
    for (int k = 0; k < 16; k++) {
      float4 a4 = *(const float4*)&As[k][ty * 4];
      float4 b4 = *(const float4*)&Bs[k][tx * 4];
      float ar[4] = {a4.x, a4.y, a4.z, a4.w};
      float br[4] = {b4.x, b4.y, b4.z, b4.w};
#pragma unroll
      for (int i = 0; i < 4; i++)
#pragma unroll
        for (int j = 0; j < 4; j++) acc[i][j] = fmaf(ar[i], br[j], acc[i][j]);
    }
    __syncthreads();
  }
  float4 bv = *(const float4*)&bias[n0 + tx * 4];
  float bb[4] = {bv.x, bv.y, bv.z, bv.w};
#pragma unroll
  for (int i = 0; i < 4; i++) {
    float o[4];
#pragma unroll
    for (int j = 0; j < 4; j++) {
      float v = acc[i][j] + bb[j];
      if (ACT == 1) v = fmaxf(v, 0.f);
      if (ACT == 2) v = tanhf(v);
      o[j] = v;
    }
    *(float4*)&C[(size_t)(m0 + ty * 4 + i) * N + n0 + tx * 4] = float4{o[0], o[1], o[2], o[3]};
  }
}

// ---------------------------------------------------------------------------
// xg GEMM: xg[dir][s*B+b, g] = dot(x[b, s_eff, :], W_ih[dir][g,:]) + b_ih[dir][g]
// s_eff = s (fwd) / S-1-s (bwd). M=S*B=12800, N=1536, K=1024. grid (24,200,2).
// ---------------------------------------------------------------------------
__global__ __launch_bounds__(256) void gemm_xg(const float* __restrict__ x,
                                               const float* __restrict__ Wf,
                                               const float* __restrict__ bf,
                                               const float* __restrict__ Wb,
                                               const float* __restrict__ bb,
                                               float* __restrict__ xgf,
                                               float* __restrict__ xgb) {
  __shared__ float As[16][68];
  __shared__ float Bs[16][68];
  const int dir = blockIdx.z;
  const float* W = dir ? Wb : Wf;
  const float* bias = dir ? bb : bf;
  float* out = dir ? xgb : xgf;
  const int t = threadIdx.x;
  const int tx = t & 15, ty = t >> 4;
  const int m0 = blockIdx.y * 64, n0 = blockIdx.x * 64;
  const int lr = t >> 2, lc = t & 3;
  const int s = m0 >> 8;           // 64-row tile lies within one s (256 = 4*64)
  const int b_base = m0 & 255;
  const int s_eff = dir ? (S_ - 1 - s) : s;
  const float* Arow = x + ((size_t)(b_base + lr) * S_ + s_eff) * I_;
  const float* Wrow = W + (size_t)(n0 + lr) * I_;
  float acc[4][4] = {};
  for (int kc = 0; kc < I_; kc += 16) {
    float4 av = *(const float4*)(Arow + kc + lc * 4);
    float4 wv = *(const float4*)(Wrow + kc + lc * 4);
    As[lc * 4 + 0][lr] = av.x; As[lc * 4 + 1][lr] = av.y;
    As[lc * 4 + 2][lr] = av.z; As[lc * 4 + 3][lr] = av.w;
    Bs[lc * 4 + 0][lr] = wv.x; Bs[lc * 4 + 1][lr] = wv.y;
    Bs[lc * 4 + 2][lr] = wv.z; Bs[lc * 4 + 3][lr] = wv.w;
    __syncthreads();
#pragma unroll
    for (int k = 0; k < 16; k++) {
      float4 a4 = *(const float4*)&As[k][ty * 4];
      float4 b4 = *(const float4*)&Bs[k][tx * 4];
      float ar[4] = {a4.x, a4.y, a4.z, a4.w};
      float br[4] = {b4.x, b4.y, b4.z, b4.w};
#pragma unroll
      for (int i = 0; i < 4; i++)
#pragma unroll
        for (int j = 0; j < 4; j++) acc[i][j] = fmaf(ar[i], br[j], acc[i][j]);
    }
    __syncthreads();
  }
  float4 bv = *(const float4*)&bias[n0 + tx * 4];
  float bb4[4] = {bv.x, bv.y, bv.z, bv.w};
#pragma unroll
  for (int i = 0; i < 4; i++) {
    float o[4];
#pragma unroll
    for (int j = 0; j < 4; j++) o[j] = acc[i][j] + bb4[j];
    *(float4*)&out[(size_t)(m0 + ty * 4 + i) * G3_ + n0 + tx * 4] = float4{o[0], o[1], o[2], o[3]};
  }
}

// ---------------------------------------------------------------------------
// One GRU time step, both directions fused. grid (16 jtiles, 8 btiles, 2 dirs),
// 192 threads. Per block: hg tile (32 b x 32 j x 3 gates), K=512 staged in LDS,
// then gates + h update in epilogue. h ping-pong between t's.
// ---------------------------------------------------------------------------
__global__ __launch_bounds__(192) void gru_step(
    const float* __restrict__ xgf, const float* __restrict__ xgb,
    const float* __restrict__ Whhf, const float* __restrict__ Whhb,
    const float* __restrict__ bhhf, const float* __restrict__ bhhb,
    const float* __restrict__ hprev_f, const float* __restrict__ hprev_b,
    float* __restrict__ hnext_f, float* __restrict__ hnext_b,
    float* __restrict__ rnn, int t) {
  __shared__ float Hs[32][36];   // [k][b_local]
  __shared__ float Ws[32][100];  // [k][col], col = gate*32 + j_local ; reused as hg[b][col]
  const int dir = blockIdx.z;
  const int b0 = blockIdx.y * 32;
  const int j0 = blockIdx.x * 32;
  const float* xg = dir ? xgb : xgf;
  const float* Whh = dir ? Whhb : Whhf;
  const float* bhh = dir ? bhhb : bhhf;
  const float* hp = dir ? hprev_b : hprev_f;
  float* hn = dir ? hnext_b : hnext_f;
  const int tid = threadIdx.x;
  const int bg = tid & 7, cg = tid >> 3;  // bg: 8 groups of 4 b; cg: 24 groups of 4 cols
  float acc[4][4] = {};
  for (int kc = 0; kc < H_; kc += 32) {
    for (int idx = tid; idx < 256; idx += 192) {  // 32 b x 8 float4
      int row = idx >> 3, f4 = idx & 7;
      float4 v = *(const float4*)&hp[(size_t)(b0 + row) * H_ + kc + f4 * 4];
      int k = f4 * 4;
      Hs[k + 0][row] = v.x; Hs[k + 1][row] = v.y; Hs[k + 2][row] = v.z; Hs[k + 3][row] = v.w;
    }
    for (int idx = tid; idx < 768; idx += 192) {  // 96 cols x 8 float4
      int c = idx >> 3, f4 = idx & 7;
      int gate = c >> 5, jl = c & 31;
      float4 v = *(const float4*)&Whh[(size_t)(gate * H_ + j0 + jl) * H_ + kc + f4 * 4];
      int k = f4 * 4;
      Ws[k + 0][c] = v.x; Ws[k + 1][c] = v.y; Ws[k + 2][c] = v.z; Ws[k + 3][c] = v.w;
    }
    __syncthreads();
#pragma unroll
    for (int k = 0; k < 32; k++) {
      float4 h4 = *(const float4*)&Hs[k][bg * 4];
      float4 w4 = *(const float4*)&Ws[k][cg * 4];
      float hr[4] = {h4.x, h4.y, h4.z, h4.w};
      float wr[4] = {w4.x, w4.y, w4.z, w4.w};
#pragma unroll
      for (int bi = 0; bi < 4; bi++)
#pragma unroll
        for (int ci = 0; ci < 4; ci++) acc[bi][ci] = fmaf(hr[bi], wr[ci], acc[bi][ci]);
    }
    __syncthreads();
  }
  // scatter hg into LDS (reuse Ws as [b_local][col])
#pragma unroll
  for (int bi = 0; bi < 4; bi++)
#pragma unroll
    for (int ci = 0; ci < 4; ci++) Ws[bg * 4 + bi][cg * 4 + ci] = acc[bi][ci];
  __syncthreads();
  const int s_orig = dir ? (S_ - 1 - t) : t;
  for (int idx = tid; idx < 1024; idx += 192) {
    int bl = idx >> 5, jl = idx & 31;
    int b = b0 + bl, j = j0 + jl;
    float hg_r = Ws[bl][jl] + bhh[j];
    float hg_z = Ws[bl][32 + jl] + bhh[H_ + j];
    float hg_n = Ws[bl][64 + jl] + bhh[2 * H_ + j];
    const float* xr = xg + ((size_t)t * B_ + b) * G3_;
    float r = sigf(xr[j] + hg_r);
    float z = sigf(xr[H_ + j] + hg_z);
    float n = tanhf(xr[2 * H_ + j] + r * hg_n);
    float hpv = hp[(size_t)b * H_ + j];
    float h = (1.f - z) * n + z * hpv;
    hn[(size_t)b * H_ + j] = h;
    rnn[((size_t)b * S_ + s_orig) * (2 * H_) + dir * H_ + j] = h;
  }
}

// avg[b][d] = sum_s sent[b][s][d] / ns[b].  grid B, block 128 (x4 cols via float4)
__global__ __launch_bounds__(128) void avg_kernel(const float* __restrict__ sent,
                                                  const int* __restrict__ ns,
                                                  float* __restrict__ avg) {
  int b = blockIdx.x, tid = threadIdx.x;
  const float* base = sent + (size_t)b * S_ * SENT_ + tid * 4;
  float4 a = {0.f, 0.f, 0.f, 0.f};
  for (int s = 0; s < S_; s++) {
    float4 v = *(const float4*)(base + (size_t)s * SENT_);
    a.x += v.x; a.y += v.y; a.z += v.z; a.w += v.w;
  }
  float inv = 1.0f / (float)ns[b];
  *(float4*)&avg[(size_t)b * SENT_ + tid * 4] = float4{a.x * inv, a.y * inv, a.z * inv, a.w * inv};
}

// tiny: pos_logits[50], seg_vals[5]
__global__ void posseg_kernel(const float* __restrict__ pos_emb, const float* __restrict__ pos_lin,
                              const float* __restrict__ seg_emb, const float* __restrict__ seg_lin,
                              float* __restrict__ pos_logits, float* __restrict__ seg_vals) {
  int tid = threadIdx.x;
  if (tid < S_) {
    int idx = tid + 1; if (idx > 25) idx = 25;
    float a = 0.f;
    for (int k = 0; k < 50; k++) a += pos_emb[idx * 50 + k] * pos_lin[k];
    pos_logits[tid] = a;
  }
  if (tid < 5) {
    float a = 0.f;
    for (int k = 0; k < 50; k++) a += seg_emb[tid * 50 + k] * seg_lin[k];
    seg_vals[tid] = a;
  }
}

// static[s*B+b] = content + salience + pos + seg + bias.  grid B*S, 1 wave each.
__global__ __launch_bounds__(64) void static_kernel(
    const float* __restrict__ sent, const float* __restrict__ doc,
    const float* __restrict__ wcont, const float* __restrict__ bcont,
    const int* __restrict__ ns, const float* __restrict__ pos_logits,
    const float* __restrict__ seg_vals, const float* __restrict__ bias,
    float* __restrict__ st) {
  int bs = blockIdx.x;
  int b = bs / S_, s = bs % S_;
  int lane = threadIdx.x;
  const float* sr = sent + (size_t)bs * SENT_;
  const float* dr = doc + (size_t)b * SENT_;
  float a0 = 0.f, a1 = 0.f;
#pragma unroll
  for (int ii = 0; ii < 8; ii++) {
    int k = ii * 64 + lane;
    float v = sr[k];
    a0 += v * wcont[k];
    a1 += v * dr[k];
  }
#pragma unroll
  for (int off = 32; off; off >>= 1) {
    a0 += __shfl_down(a0, off);
    a1 += __shfl_down(a1, off);
  }
  if (lane == 0) {
    float chunk = rintf((float)ns[b] * 0.25f);
    float relf = ceilf((float)(s + 1) / chunk);
    relf = fminf(fmaxf(relf, 0.f), 4.f);
    int rel = (int)relf;
    st[s * B_ + b] = a0 + bcont[0] + a1 + pos_logits[s] + seg_vals[rel] + bias[0];
  }
}

// One novelty-scan step. grid B, block 256. summary must be zeroed before t=0.
__global__ __launch_bounds__(256) void novelty_step(
    const float* __restrict__ sent, const float* __restrict__ st,
    const float* __restrict__ Wsim, float* __restrict__ summary,
    float* __restrict__ out, int t) {
  __shared__ float ts[512];
  __shared__ float wred[4];
  int b = blockIdx.x, tid = threadIdx.x;
  float s0 = summary[(size_t)b * SENT_ + tid];
  float s1 = summary[(size_t)b * SENT_ + 256 + tid];
  ts[tid] = tanhf(s0);
  ts[256 + tid] = tanhf(s1);
  __syncthreads();
  const float* sb = sent + ((size_t)b * S_ + t) * SENT_;
  float partial = 0.f;
#pragma unroll
  for (int ii = 0; ii < 2; ii++) {
    int i = tid * 2 + ii;
    const float4* wr = (const float4*)(Wsim + (size_t)i * SENT_);
    float u = 0.f;
#pragma unroll 8
    for (int kv = 0; kv < 128; kv++) {
      float4 w = wr[kv];
      u += w.x * ts[kv * 4] + w.y * ts[kv * 4 + 1] + w.z * ts[kv * 4 + 2] + w.w * ts[kv * 4 + 3];
    }
    partial += sb[i] * u;
  }
#pragma unroll
  for (int off = 32; off; off >>= 1) partial += __shfl_down(partial, off);
  if ((tid & 63) == 0) wred[tid >> 6] = partial;
  __syncthreads();
  float sim = wred[0] + wred[1] + wred[2] + wred[3];
  float logit = st[t * B_ + b] - sim;
  if (tid == 0) out[(size_t)t * B_ + b] = logit;
  float sg = sigf(logit);
  summary[(size_t)b * SENT_ + tid] = s0 + sb[tid] * sg;
  summary[(size_t)b * SENT_ + 256 + tid] = s1 + sb[256 + tid] * sg;
}

extern "C" void kernel_launch(void* const* d_in, const int* in_sizes, int n_in,
                              void* d_out, int out_size, void* d_ws, size_t ws_size,
                              hipStream_t stream) {
  const float* x = (const float*)d_in[0];
  const int* ns = (const int*)d_in[1];
  const float* Wihf = (const float*)d_in[2];
  const float* Whhf = (const float*)d_in[3];
  const float* bihf = (const float*)d_in[4];
  const float* bhhf = (const float*)d_in[5];
  const float* Wihb = (const float*)d_in[6];
  const float* Whhb = (const float*)d_in[7];
  const float* bihb = (const float*)d_in[8];
  const float* bhhb = (const float*)d_in[9];
  const float* Wsent = (const float*)d_in[10];
  const float* bsent = (const float*)d_in[11];
  const float* wcont = (const float*)d_in[12];
  const float* bcont = (const float*)d_in[13];
  const float* Wd1 = (const float*)d_in[14];
  const float* bd1 = (const float*)d_in[15];
  const float* Wd2 = (const float*)d_in[16];
  const float* bd2 = (const float*)d_in[17];
  const float* Wsim = (const float*)d_in[18];
  const float* bias = (const float*)d_in[19];
  const float* pos_emb = (const float*)d_in[20];
  const float* pos_lin = (const float*)d_in[21];
  const float* seg_emb = (const float*)d_in[22];
  const float* seg_lin = (const float*)d_in[23];
  float* out = (float*)d_out;
  float* ws = (float*)d_ws;

  size_t off = 0;
  float* xgf = ws + off;     off += (size_t)S_ * B_ * G3_;       // 19,660,800
  float* xgb = ws + off;     off += (size_t)S_ * B_ * G3_;
  float* rnn = ws + off;     off += (size_t)B_ * S_ * 2 * H_;    // 13,107,200
  float* sent = ws + off;    off += (size_t)B_ * S_ * SENT_;     //  6,553,600
  float* hbufs = ws + off;   off += 4 * (size_t)B_ * H_;         // [dir][pp][B][H]
  float* summary = ws + off; off += (size_t)B_ * SENT_;
  float* avg = ws + off;     off += (size_t)B_ * SENT_;
  float* d1buf = ws + off;   off += (size_t)B_ * DOC_;
  float* doc = ws + off;     off += (size_t)B_ * SENT_;
  float* st = ws + off;      off += (size_t)S_ * B_;
  float* poslog = ws + off;  off += 64;
  float* segvals = ws + off; off += 8;

  // zero h ping-pong buffers + summary (contiguous)
  hipMemsetAsync(hbufs, 0, (4 * (size_t)B_ * H_ + (size_t)B_ * SENT_) * sizeof(float), stream);

  // input-gate GEMMs, both directions
  gemm_xg<<<dim3(G3_ / 64, (S_ * B_) / 64, 2), 256, 0, stream>>>(x, Wihf, bihf, Wihb, bihb, xgf, xgb);
  posseg_kernel<<<1, 64, 0, stream>>>(pos_emb, pos_lin, seg_emb, seg_lin, poslog, segvals);

  // GRU scan (fwd+bwd fused per step), h ping-pong
  const size_t hsz = (size_t)B_ * H_;
  for (int t = 0; t < S_; t++) {
    int pp = t & 1;
    float* hpf = hbufs + (0 * 2 + pp) * hsz;
    float* hnf = hbufs + (0 * 2 + (pp ^ 1)) * hsz;
    float* hpb = hbufs + (2 + pp) * hsz;
    float* hnb = hbufs + (2 + (pp ^ 1)) * hsz;
    gru_step<<<dim3(H_ / 32, B_ / 32, 2), 192, 0, stream>>>(xgf, xgb, Whhf, Whhb, bhhf, bhhb,
                                                            hpf, hpb, hnf, hnb, rnn, t);
  }

  // sent = relu(rnn @ Wsent.T + bsent)
  gemm_nt<1><<<dim3(SENT_ / 64, (B_ * S_) / 64), 256, 0, stream>>>(rnn, Wsent, bsent, sent, SENT_, 2 * H_);
  avg_kernel<<<B_, 128, 0, stream>>>(sent, ns, avg);
  gemm_nt<2><<<dim3(DOC_ / 64, B_ / 64), 256, 0, stream>>>(avg, Wd1, bd1, d1buf, DOC_, SENT_);
  gemm_nt<0><<<dim3(SENT_ / 64, B_ / 64), 256, 0, stream>>>(d1buf, Wd2, bd2, doc, SENT_, DOC_);
  static_kernel<<<B_ * S_, 64, 0, stream>>>(sent, doc, wcont, bcont, ns, poslog, segvals, bias, st);

  // sequential novelty scan
  for (int t = 0; t < S_; t++)
    novelty_step<<<B_, 256, 0, stream>>>(sent, st, Wsim, summary, out, t);
}

// Round 2
// 1289.087 us; speedup vs baseline: 4.1507x; 4.1507x over previous
//
#include <hip/hip_runtime.h>
#include <hip/hip_bf16.h>
#include <math.h>

#define B_    256
#define S_    50
#define I_    1024
#define H_    512
#define G3_   1536   // 3*H
#define SENT_ 512
#define DOC_  1024

typedef short bf16x8 __attribute__((ext_vector_type(8)));
typedef float f32x4 __attribute__((ext_vector_type(4)));

__device__ __forceinline__ float sigf(float x) { return 1.0f / (1.0f + __expf(-x)); }

// async global->LDS, 16B per lane. LDS dest = wave-uniform base + lane*16.
__device__ __forceinline__ void gload16(const void* g, void* l) {
  __builtin_amdgcn_global_load_lds((const __attribute__((address_space(1))) void*)g,
                                   (__attribute__((address_space(3))) void*)l, 16, 0, 0);
}

// ===========================================================================
// bf16 MFMA GEMM core conventions (m97 structure):
//  - tiles 128(M) x 128(N), BK=64, 256 threads = 4 waves, each wave 64x64.
//  - LDS layout: row-major [rows][64] bf16, 8 k-groups of 8 bf16 per row,
//    k-group slot XOR-swizzled with (row&7) -> ds_read_b128 2-way only.
//  - frag load: row = lane&15, kgroup = ks*4 + (lane>>4); A and W symmetric.
//  - C/D: col = lane&15 (n), row = (lane>>4)*4 + reg (m)   [m89-verified]
// ===========================================================================

// xg GEMM: A-rows mapped (b, s_eff); out = bf16 xg[dir][t*B+b][3H], bias added.
__global__ __launch_bounds__(256) void mfma_xg(
    const __hip_bfloat16* __restrict__ x,
    const __hip_bfloat16* __restrict__ Wf, const float* __restrict__ bf_,
    const __hip_bfloat16* __restrict__ Wb, const float* __restrict__ bb_,
    __hip_bfloat16* __restrict__ xgf, __hip_bfloat16* __restrict__ xgb) {
  __shared__ __align__(16) short As[128 * 64];
  __shared__ __align__(16) short Ws[128 * 64];
  const int dir = blockIdx.z;
  const __hip_bfloat16* W = dir ? Wb : Wf;
  const float* bias = dir ? bb_ : bf_;
  __hip_bfloat16* out = dir ? xgb : xgf;
  const int tid = threadIdx.x;
  const int m0 = blockIdx.y * 128, n0 = blockIdx.x * 128;
  const int s = blockIdx.y >> 1, b_base = (blockIdx.y & 1) * 128;
  const int s_eff = dir ? (S_ - 1 - s) : s;
  const int lane = tid & 63, w = tid >> 6;
  const int moff = (w & 1) * 64, noff = (w >> 1) * 64;
  const int frow = lane & 15, quad = lane >> 4;
  const int rr = tid >> 3, gs = tid & 7;
  f32x4 acc[4][4] = {};
  for (int kc = 0; kc < I_; kc += 64) {
#pragma unroll
    for (int iss = 0; iss < 4; iss++) {
      int r = iss * 32 + rr;
      int col = kc + ((gs ^ (r & 7)) << 3);
      gload16(x + ((size_t)(b_base + r) * S_ + s_eff) * I_ + col, &As[(iss * 256 + w * 64) * 8]);
    }
#pragma unroll
    for (int iss = 0; iss < 4; iss++) {
      int r = iss * 32 + rr;
      int col = kc + ((gs ^ (r & 7)) << 3);
      gload16(W + (size_t)(n0 + r) * I_ + col, &Ws[(iss * 256 + w * 64) * 8]);
    }
    __syncthreads();
#pragma unroll
    for (int ks = 0; ks < 2; ks++) {
      int kg = ks * 4 + quad;
      bf16x8 af[4], bfr[4];
#pragma unroll
      for (int mf = 0; mf < 4; mf++) {
        int r = moff + mf * 16 + frow;
        af[mf] = *(const bf16x8*)&As[(r * 8 + (kg ^ (r & 7))) * 8];
      }
#pragma unroll
      for (int nf = 0; nf < 4; nf++) {
        int r = noff + nf * 16 + frow;
        bfr[nf] = *(const bf16x8*)&Ws[(r * 8 + (kg ^ (r & 7))) * 8];
      }
#pragma unroll
      for (int mf = 0; mf < 4; mf++)
#pragma unroll
        for (int nf = 0; nf < 4; nf++)
          acc[mf][nf] = __builtin_amdgcn_mfma_f32_16x16x32_bf16(af[mf], bfr[nf], acc[mf][nf], 0, 0, 0);
    }
    __syncthreads();
  }
#pragma unroll
  for (int mf = 0; mf < 4; mf++) {
    int rowb = m0 + moff + mf * 16 + quad * 4;
#pragma unroll
    for (int nf = 0; nf < 4; nf++) {
      int col = n0 + noff + nf * 16 + frow;
      float bv = bias[col];
      f32x4 c = acc[mf][nf];
#pragma unroll
      for (int rg = 0; rg < 4; rg++)
        out[(size_t)(rowb + rg) * G3_ + col] = __float2bfloat16(c[rg] + bv);
    }
  }
}

// generic bf16 GEMM: C = act(A @ W.T + bias). A[M,K], W[N,K] bf16. out bf16.
template <int ACT, bool HASBIAS>
__global__ __launch_bounds__(256) void mfma_nt(
    const __hip_bfloat16* __restrict__ A, const __hip_bfloat16* __restrict__ W,
    const float* __restrict__ bias, __hip_bfloat16* __restrict__ outb, int N, int K) {
  __shared__ __align__(16) short As[128 * 64];
  __shared__ __align__(16) short Ws[128 * 64];
  const int tid = threadIdx.x;
  const int m0 = blockIdx.y * 128, n0 = blockIdx.x * 128;
  const int lane = tid & 63, w = tid >> 6;
  const int moff = (w & 1) * 64, noff = (w >> 1) * 64;
  const int frow = lane & 15, quad = lane >> 4;
  const int rr = tid >> 3, gs = tid & 7;
  f32x4 acc[4][4] = {};
  for (int kc = 0; kc < K; kc += 64) {
#pragma unroll
    for (int iss = 0; iss < 4; iss++) {
      int r = iss * 32 + rr;
      int col = kc + ((gs ^ (r & 7)) << 3);
      gload16(A + (size_t)(m0 + r) * K + col, &As[(iss * 256 + w * 64) * 8]);
    }
#pragma unroll
    for (int iss = 0; iss < 4; iss++) {
      int r = iss * 32 + rr;
      int col = kc + ((gs ^ (r & 7)) << 3);
      gload16(W + (size_t)(n0 + r) * K + col, &Ws[(iss * 256 + w * 64) * 8]);
    }
    __syncthreads();
#pragma unroll
    for (int ks = 0; ks < 2; ks++) {
      int kg = ks * 4 + quad;
      bf16x8 af[4], bfr[4];
#pragma unroll
      for (int mf = 0; mf < 4; mf++) {
        int r = moff + mf * 16 + frow;
        af[mf] = *(const bf16x8*)&As[(r * 8 + (kg ^ (r & 7))) * 8];
      }
#pragma unroll
      for (int nf = 0; nf < 4; nf++) {
        int r = noff + nf * 16 + frow;
        bfr[nf] = *(const bf16x8*)&Ws[(r * 8 + (kg ^ (r & 7))) * 8];
      }
#pragma unroll
      for (int mf = 0; mf < 4; mf++)
#pragma unroll
        for (int nf = 0; nf < 4; nf++)
          acc[mf][nf] = __builtin_amdgcn_mfma_f32_16x16x32_bf16(af[mf], bfr[nf], acc[mf][nf], 0, 0, 0);
    }
    __syncthreads();
  }
#pragma unroll
  for (int mf = 0; mf < 4; mf++) {
    int rowb = m0 + moff + mf * 16 + quad * 4;
#pragma unroll
    for (int nf = 0; nf < 4; nf++) {
      int col = n0 + noff + nf * 16 + frow;
      float bv = HASBIAS ? bias[col] : 0.f;
      f32x4 c = acc[mf][nf];
#pragma unroll
      for (int rg = 0; rg < 4; rg++) {
        float v = c[rg] + bv;
        if (ACT == 1) v = fmaxf(v, 0.f);
        outb[(size_t)(rowb + rg) * N + col] = __float2bfloat16(v);
      }
    }
  }
}

// ---------------------------------------------------------------------------
// GRU step, MFMA. W_hh pre-packed: row p = (j>>5)*96 + g*32 + (j&31), so one
// 96-col N-tile = all 3 gates for a 32-j slice. Wave layout: moff=(w&1)*64,
// jlh=(w>>1)*16; n-frags are the 3 gates at col g*32+jlh -> for a fixed lane
// the gate triple (r,z,n) shares j = j0+jlh+(lane&15) -> gate math in-register.
// grid (16 j-tiles, 2 b-tiles, 2 dirs), 256 threads.
// ---------------------------------------------------------------------------
__global__ __launch_bounds__(256) void gru_step_mfma(
    const __hip_bfloat16* __restrict__ xgf, const __hip_bfloat16* __restrict__ xgb,
    const __hip_bfloat16* __restrict__ Wpf, const __hip_bfloat16* __restrict__ Wpb,
    const float* __restrict__ bhhf, const float* __restrict__ bhhb,
    const float* __restrict__ hpf32, const float* __restrict__ hpb32,
    const __hip_bfloat16* __restrict__ hpf16, const __hip_bfloat16* __restrict__ hpb16,
    float* __restrict__ hnf32, float* __restrict__ hnb32,
    __hip_bfloat16* __restrict__ hnf16, __hip_bfloat16* __restrict__ hnb16,
    __hip_bfloat16* __restrict__ rnn, int t) {
  __shared__ __align__(16) short As[128 * 64];
  __shared__ __align__(16) short Ws[96 * 64];
  const int dir = blockIdx.z;
  const __hip_bfloat16* xg = dir ? xgb : xgf;
  const __hip_bfloat16* Wp = dir ? Wpb : Wpf;
  const float* bhh = dir ? bhhb : bhhf;
  const float* hp32 = dir ? hpb32 : hpf32;
  const __hip_bfloat16* hp16 = dir ? hpb16 : hpf16;
  float* hn32 = dir ? hnb32 : hnf32;
  __hip_bfloat16* hn16 = dir ? hnb16 : hnf16;
  const int b0 = blockIdx.y * 128;
  const int j0 = blockIdx.x * 32;
  const int n0p = blockIdx.x * 96;
  const int tid = threadIdx.x;
  const int lane = tid & 63, w = tid >> 6;
  const int moff = (w & 1) * 64;
  const int jlh = (w >> 1) * 16;
  const int frow = lane & 15, quad = lane >> 4;
  const int rr = tid >> 3, gs = tid & 7;
  f32x4 acc[4][3] = {};
  for (int kc = 0; kc < H_; kc += 64) {
#pragma unroll
    for (int iss = 0; iss < 4; iss++) {
      int r = iss * 32 + rr;
      int col = kc + ((gs ^ (r & 7)) << 3);
      gload16(hp16 + (size_t)(b0 + r) * H_ + col, &As[(iss * 256 + w * 64) * 8]);
    }
#pragma unroll
    for (int iss = 0; iss < 3; iss++) {
      int r = iss * 32 + rr;
      int col = kc + ((gs ^ (r & 7)) << 3);
      gload16(Wp + (size_t)(n0p + r) * H_ + col, &Ws[(iss * 256 + w * 64) * 8]);
    }
    __syncthreads();
#pragma unroll
    for (int ks = 0; ks < 2; ks++) {
      int kg = ks * 4 + quad;
      bf16x8 af[4], bfr[3];
#pragma unroll
      for (int mf = 0; mf < 4; mf++) {
        int r = moff + mf * 16 + frow;
        af[mf] = *(const bf16x8*)&As[(r * 8 + (kg ^ (r & 7))) * 8];
      }
#pragma unroll
      for (int g = 0; g < 3; g++) {
        int r = g * 32 + jlh + frow;
        bfr[g] = *(const bf16x8*)&Ws[(r * 8 + (kg ^ (r & 7))) * 8];
      }
#pragma unroll
      for (int mf = 0; mf < 4; mf++)
#pragma unroll
        for (int g = 0; g < 3; g++)
          acc[mf][g] = __builtin_amdgcn_mfma_f32_16x16x32_bf16(af[mf], bfr[g], acc[mf][g], 0, 0, 0);
    }
    __syncthreads();
  }
  const int s_orig = dir ? (S_ - 1 - t) : t;
  const int j = j0 + jlh + frow;
  const float br = bhh[j], bz = bhh[H_ + j], bn = bhh[2 * H_ + j];
#pragma unroll
  for (int mf = 0; mf < 4; mf++) {
#pragma unroll
    for (int rg = 0; rg < 4; rg++) {
      int b = b0 + moff + mf * 16 + quad * 4 + rg;
      const __hip_bfloat16* xr = xg + ((size_t)t * B_ + b) * G3_;
      float r = sigf(__bfloat162float(xr[j]) + acc[mf][0][rg] + br);
      float z = sigf(__bfloat162float(xr[H_ + j]) + acc[mf][1][rg] + bz);
      float n = tanhf(__bfloat162float(xr[2 * H_ + j]) + r * (acc[mf][2][rg] + bn));
      float hpv = hp32[(size_t)b * H_ + j];
      float h = (1.f - z) * n + z * hpv;
      hn32[(size_t)b * H_ + j] = h;
      __hip_bfloat16 hb = __float2bfloat16(h);
      hn16[(size_t)b * H_ + j] = hb;
      rnn[((size_t)b * S_ + s_orig) * (2 * H_) + dir * H_ + j] = hb;
    }
  }
}

// ---------------------------------------------------------------------------
// fp32 tiled GEMM (kept for the small doc GEMMs, M=256)
// ---------------------------------------------------------------------------
template <int ACT>
__global__ __launch_bounds__(256) void gemm_nt(const float* __restrict__ A,
                                               const float* __restrict__ W,
                                               const float* __restrict__ bias,
                                               float* __restrict__ C, int N, int K) {
  __shared__ float As[16][68];
  __shared__ float Bs[16][68];
  const int t = threadIdx.x;
  const int tx = t & 15, ty = t >> 4;
  const int m0 = blockIdx.y * 64, n0 = blockIdx.x * 64;
  const int lr = t >> 2, lc = t & 3;
  const float* Arow = A + (size_t)(m0 + lr) * K;
  const float* Wrow = W + (size_t)(n0 + lr) * K;
  float acc[4][4] = {};
  for (int kc = 0; kc < K; kc += 16) {
    float4 av = *(const float4*)(Arow + kc + lc * 4);
    float4 wv = *(const float4*)(Wrow + kc + lc * 4);
    As[lc * 4 + 0][lr] = av.x; As[lc * 4 + 1][lr] = av.y;
    As[lc * 4 + 2][lr] = av.z; As[lc * 4 + 3][lr] = av.w;
    Bs[lc * 4 + 0][lr] = wv.x; Bs[lc * 4 + 1][lr] = wv.y;
    Bs[lc * 4 + 2][lr] = wv.z; Bs[lc * 4 + 3][lr] = wv.w;
    __syncthreads();
#pragma unroll
    for (int k = 0; k < 16; k++) {
      float4 a4 = *(const float4*)&As[k][ty * 4];
      float4 b4 = *(const float4*)&Bs[k][tx * 4];
      float ar[4] = {a4.x, a4.y, a4.z, a4.w};
      float br[4] = {b4.x, b4.y, b4.z, b4.w};
#pragma unroll
      for (int i = 0; i < 4; i++)
#pragma unroll
        for (int j = 0; j < 4; j++) acc[i][j] = fmaf(ar[i], br[j], acc[i][j]);
    }
    __syncthreads();
  }
  float4 bv = *(const float4*)&bias[n0 + tx * 4];
  float bb[4] = {bv.x, bv.y, bv.z, bv.w};
#pragma unroll
  for (int i = 0; i < 4; i++) {
    float o[4];
#pragma unroll
    for (int j = 0; j < 4; j++) {
      float v = acc[i][j] + bb[j];
      if (ACT == 1) v = fmaxf(v, 0.f);
      if (ACT == 2) v = tanhf(v);
      o[j] = v;
    }
    *(float4*)&C[(size_t)(m0 + ty * 4 + i) * N + n0 + tx * 4] = float4{o[0], o[1], o[2], o[3]};
  }
}

// ------------------------- small helper kernels ----------------------------
__global__ void cast_kernel(const float* __restrict__ in, __hip_bfloat16* __restrict__ out, int n) {
  int i = (blockIdx.x * blockDim.x + threadIdx.x) * 4;
  if (i + 3 < n) {
    float4 v = *(const float4*)(in + i);
    out[i + 0] = __float2bfloat16(v.x);
    out[i + 1] = __float2bfloat16(v.y);
    out[i + 2] = __float2bfloat16(v.z);
    out[i + 3] = __float2bfloat16(v.w);
  }
}

__global__ void pack_whh(const float* __restrict__ Whh, __hip_bfloat16* __restrict__ outp) {
  int idx = blockIdx.x * 256 + threadIdx.x;  // 1536*512 total
  if (idx >= G3_ * H_) return;
  int k = idx & 511;
  int row = idx >> 9;          // g*512 + j
  int g = row >> 9, j = row & 511;
  int p = (j >> 5) * 96 + g * 32 + (j & 31);
  outp[(size_t)p * H_ + k] = __float2bfloat16(Whh[idx]);
}

__global__ void tcast_wsim(const float* __restrict__ Wsim, __hip_bfloat16* __restrict__ outT) {
  int idx = blockIdx.x * 256 + threadIdx.x;  // 512*512
  if (idx >= SENT_ * SENT_) return;
  int i = idx >> 9, j = idx & 511;
  outT[(size_t)j * SENT_ + i] = __float2bfloat16(Wsim[idx]);
}

__global__ __launch_bounds__(256) void avg_kernel(const __hip_bfloat16* __restrict__ sent,
                                                  const int* __restrict__ ns,
                                                  float* __restrict__ avg) {
  int b = blockIdx.x, tid = threadIdx.x;
  const __hip_bfloat16* base = sent + (size_t)b * S_ * SENT_;
  float a0 = 0.f, a1 = 0.f;
  for (int s = 0; s < S_; s++) {
    a0 += __bfloat162float(base[s * SENT_ + tid]);
    a1 += __bfloat162float(base[s * SENT_ + 256 + tid]);
  }
  float inv = 1.0f / (float)ns[b];
  avg[(size_t)b * SENT_ + tid] = a0 * inv;
  avg[(size_t)b * SENT_ + 256 + tid] = a1 * inv;
}

__global__ void posseg_kernel(const float* __restrict__ pos_emb, const float* __restrict__ pos_lin,
                              const float* __restrict__ seg_emb, const float* __restrict__ seg_lin,
                              float* __restrict__ pos_logits, float* __restrict__ seg_vals) {
  int tid = threadIdx.x;
  if (tid < S_) {
    int idx = tid + 1; if (idx > 25) idx = 25;
    float a = 0.f;
    for (int k = 0; k < 50; k++) a += pos_emb[idx * 50 + k] * pos_lin[k];
    pos_logits[tid] = a;
  }
  if (tid < 5) {
    float a = 0.f;
    for (int k = 0; k < 50; k++) a += seg_emb[tid * 50 + k] * seg_lin[k];
    seg_vals[tid] = a;
  }
}

__global__ __launch_bounds__(64) void static_kernel(
    const __hip_bfloat16* __restrict__ sent, const float* __restrict__ doc,
    const float* __restrict__ wcont, const float* __restrict__ bcont,
    const int* __restrict__ ns, const float* __restrict__ pos_logits,
    const float* __restrict__ seg_vals, const float* __restrict__ bias,
    float* __restrict__ st) {
  int bs = blockIdx.x;
  int b = bs / S_, s = bs % S_;
  int lane = threadIdx.x;
  const __hip_bfloat16* sr = sent + (size_t)bs * SENT_;
  const float* dr = doc + (size_t)b * SENT_;
  float a0 = 0.f, a1 = 0.f;
#pragma unroll
  for (int ii = 0; ii < 8; ii++) {
    int k = ii * 64 + lane;
    float v = __bfloat162float(sr[k]);
    a0 += v * wcont[k];
    a1 += v * dr[k];
  }
#pragma unroll
  for (int off = 32; off; off >>= 1) {
    a0 += __shfl_down(a0, off);
    a1 += __shfl_down(a1, off);
  }
  if (lane == 0) {
    float chunk = rintf((float)ns[b] * 0.25f);
    float relf = ceilf((float)(s + 1) / chunk);
    relf = fminf(fmaxf(relf, 0.f), 4.f);
    int rel = (int)relf;
    st[s * B_ + b] = a0 + bcont[0] + a1 + pos_logits[s] + seg_vals[rel] + bias[0];
  }
}

// Persistent novelty scan: one block per batch element, loop over t in-kernel.
// sim_t = dot(U[b,t,:], tanh(summary)); summary += sent[b,t,:]*sigmoid(logit)
__global__ __launch_bounds__(256) void novelty_all(
    const __hip_bfloat16* __restrict__ sent, const __hip_bfloat16* __restrict__ U,
    const float* __restrict__ st, float* __restrict__ out) {
  __shared__ float wred[4];
  int b = blockIdx.x, tid = threadIdx.x;
  float s0 = 0.f, s1 = 0.f;
  for (int t = 0; t < S_; t++) {
    const __hip_bfloat16* ur = U + ((size_t)b * S_ + t) * SENT_;
    float p = __bfloat162float(ur[tid]) * tanhf(s0) +
              __bfloat162float(ur[tid + 256]) * tanhf(s1);
#pragma unroll
    for (int off = 32; off; off >>= 1) p += __shfl_down(p, off);
    if ((tid & 63) == 0) wred[tid >> 6] = p;
    __syncthreads();
    float sim = wred[0] + wred[1] + wred[2] + wred[3];
    float logit = st[t * B_ + b] - sim;
    if (tid == 0) out[(size_t)t * B_ + b] = logit;
    float sg = sigf(logit);
    const __hip_bfloat16* sr = sent + ((size_t)b * S_ + t) * SENT_;
    s0 += __bfloat162float(sr[tid]) * sg;
    s1 += __bfloat162float(sr[tid + 256]) * sg;
    __syncthreads();  // wred reuse barrier
  }
}

extern "C" void kernel_launch(void* const* d_in, const int* in_sizes, int n_in,
                              void* d_out, int out_size, void* d_ws, size_t ws_size,
                              hipStream_t stream) {
  const float* x = (const float*)d_in[0];
  const int* ns = (const int*)d_in[1];
  const float* Wihf = (const float*)d_in[2];
  const float* Whhf = (const float*)d_in[3];
  const float* bihf = (const float*)d_in[4];
  const float* bhhf = (const float*)d_in[5];
  const float* Wihb = (const float*)d_in[6];
  const float* Whhb = (const float*)d_in[7];
  const float* bihb = (const float*)d_in[8];
  const float* bhhb = (const float*)d_in[9];
  const float* Wsent = (const float*)d_in[10];
  const float* bsent = (const float*)d_in[11];
  const float* wcont = (const float*)d_in[12];
  const float* bcont = (const float*)d_in[13];
  const float* Wd1 = (const float*)d_in[14];
  const float* bd1 = (const float*)d_in[15];
  const float* Wd2 = (const float*)d_in[16];
  const float* bd2 = (const float*)d_in[17];
  const float* Wsim = (const float*)d_in[18];
  const float* bias = (const float*)d_in[19];
  const float* pos_emb = (const float*)d_in[20];
  const float* pos_lin = (const float*)d_in[21];
  const float* seg_emb = (const float*)d_in[22];
  const float* seg_lin = (const float*)d_in[23];
  float* out = (float*)d_out;

  // ---- workspace layout (bytes), total ~147.4 MB ----
  char* base = (char*)d_ws;
  size_t off = 0;
  auto alloc = [&](size_t bytes) { char* p = base + off; off += (bytes + 255) & ~255ull; return p; };
  __hip_bfloat16* xgf_b  = (__hip_bfloat16*)alloc((size_t)S_ * B_ * G3_ * 2);   // 39.3 MB
  __hip_bfloat16* xgb_b  = (__hip_bfloat16*)alloc((size_t)S_ * B_ * G3_ * 2);
  char* region1          = alloc((size_t)B_ * S_ * I_ * 2);                      // 26.2 MB: x_bf, later sent_b+U_b
  __hip_bfloat16* x_bf   = (__hip_bfloat16*)region1;
  __hip_bfloat16* sent_b = (__hip_bfloat16*)region1;                             // alias (after xg GEMM done)
  __hip_bfloat16* U_b    = (__hip_bfloat16*)(region1 + (size_t)B_ * S_ * SENT_ * 2);
  __hip_bfloat16* rnn_b  = (__hip_bfloat16*)alloc((size_t)B_ * S_ * 2 * H_ * 2); // 26.2 MB
  __hip_bfloat16* Wihf_b = (__hip_bfloat16*)alloc((size_t)G3_ * I_ * 2);
  __hip_bfloat16* Wihb_b = (__hip_bfloat16*)alloc((size_t)G3_ * I_ * 2);
  __hip_bfloat16* Wpf    = (__hip_bfloat16*)alloc((size_t)G3_ * H_ * 2);
  __hip_bfloat16* Wpb    = (__hip_bfloat16*)alloc((size_t)G3_ * H_ * 2);
  __hip_bfloat16* Wsent_b= (__hip_bfloat16*)alloc((size_t)SENT_ * 2 * H_ * 2);
  __hip_bfloat16* WsimT_b= (__hip_bfloat16*)alloc((size_t)SENT_ * SENT_ * 2);
  float* hf32            = (float*)alloc(4 * (size_t)B_ * H_ * 4);               // [dir][pp][B][H]
  __hip_bfloat16* hb16   = (__hip_bfloat16*)alloc(4 * (size_t)B_ * H_ * 2);
  float* avg             = (float*)alloc((size_t)B_ * SENT_ * 4);
  float* d1buf           = (float*)alloc((size_t)B_ * DOC_ * 4);
  float* doc             = (float*)alloc((size_t)B_ * SENT_ * 4);
  float* st              = (float*)alloc((size_t)S_ * B_ * 4);
  float* poslog          = (float*)alloc(256);
  float* segvals         = (float*)alloc(64);
  (void)ws_size;

  // h buffers (fp32 + bf16 contiguous) -> zero
  hipMemsetAsync(hf32, 0, 4 * (size_t)B_ * H_ * 4 + ((4 * (size_t)B_ * H_ * 2 + 255) & ~255ull), stream);

  // casts / packs
  cast_kernel<<<(B_ * S_ * I_ / 4 + 255) / 256, 256, 0, stream>>>(x, x_bf, B_ * S_ * I_);
  cast_kernel<<<(G3_ * I_ / 4 + 255) / 256, 256, 0, stream>>>(Wihf, Wihf_b, G3_ * I_);
  cast_kernel<<<(G3_ * I_ / 4 + 255) / 256, 256, 0, stream>>>(Wihb, Wihb_b, G3_ * I_);
  cast_kernel<<<(SENT_ * 2 * H_ / 4 + 255) / 256, 256, 0, stream>>>(Wsent, Wsent_b, SENT_ * 2 * H_);
  pack_whh<<<(G3_ * H_ + 255) / 256, 256, 0, stream>>>(Whhf, Wpf);
  pack_whh<<<(G3_ * H_ + 255) / 256, 256, 0, stream>>>(Whhb, Wpb);
  tcast_wsim<<<(SENT_ * SENT_ + 255) / 256, 256, 0, stream>>>(Wsim, WsimT_b);
  posseg_kernel<<<1, 64, 0, stream>>>(pos_emb, pos_lin, seg_emb, seg_lin, poslog, segvals);

  // xg = x @ W_ih.T + b_ih (both dirs), bf16 out
  mfma_xg<<<dim3(G3_ / 128, (S_ * B_) / 128, 2), 256, 0, stream>>>(x_bf, Wihf_b, bihf, Wihb_b, bihb, xgf_b, xgb_b);

  // GRU scan, MFMA per step, fp32+bf16 h ping-pong
  const size_t hsz = (size_t)B_ * H_;
  for (int t = 0; t < S_; t++) {
    int pp = t & 1;
    gru_step_mfma<<<dim3(16, 2, 2), 256, 0, stream>>>(
        xgf_b, xgb_b, Wpf, Wpb, bhhf, bhhb,
        hf32 + (0 * 2 + pp) * hsz, hf32 + (2 + pp) * hsz,
        hb16 + (0 * 2 + pp) * hsz, hb16 + (2 + pp) * hsz,
        hf32 + (0 * 2 + (pp ^ 1)) * hsz, hf32 + (2 + (pp ^ 1)) * hsz,
        hb16 + (0 * 2 + (pp ^ 1)) * hsz, hb16 + (2 + (pp ^ 1)) * hsz,
        rnn_b, t);
  }

  // sent = relu(rnn @ Wsent.T + b) -> bf16 (x_bf region now dead, alias ok)
  mfma_nt<1, true><<<dim3(SENT_ / 128, (B_ * S_) / 128), 256, 0, stream>>>(rnn_b, Wsent_b, bsent, sent_b, SENT_, 2 * H_);
  avg_kernel<<<B_, 256, 0, stream>>>(sent_b, ns, avg);
  gemm_nt<2><<<dim3(DOC_ / 64, B_ / 64), 256, 0, stream>>>(avg, Wd1, bd1, d1buf, DOC_, SENT_);
  gemm_nt<0><<<dim3(SENT_ / 64, B_ / 64), 256, 0, stream>>>(d1buf, Wd2, bd2, doc, SENT_, DOC_);
  static_kernel<<<B_ * S_, 64, 0, stream>>>(sent_b, doc, wcont, bcont, ns, poslog, segvals, bias, st);

  // U = sent @ W_sim  (via W_sim^T as [N,K])
  mfma_nt<0, false><<<dim3(SENT_ / 128, (B_ * S_) / 128), 256, 0, stream>>>(sent_b, WsimT_b, nullptr, U_b, SENT_, SENT_);

  // persistent novelty scan (per-b independent)
  novelty_all<<<B_, 256, 0, stream>>>(sent_b, U_b, st, out);
}